// Round 13
// baseline (698.584 us; speedup 1.0000x reference)
//
#include <hip/hip_runtime.h>
#include <hip/hip_bf16.h>
#include <math.h>

typedef unsigned short u16;
typedef __attribute__((ext_vector_type(8))) short bf16x8;
typedef __attribute__((ext_vector_type(4))) float f32x4;

__device__ __forceinline__ float b2f(u16 v) {
  unsigned u = ((unsigned)v) << 16;
  return __builtin_bit_cast(float, u);
}
__device__ __forceinline__ u16 f2b(float f) {
  unsigned u = __builtin_bit_cast(unsigned, f);
  unsigned r = u + 0x7fffu + ((u >> 16) & 1u);
  return (u16)(r >> 16);
}
__device__ __forceinline__ void gload_lds16(const u16* g, u16* l) {
  __builtin_amdgcn_global_load_lds(
      (const __attribute__((address_space(1))) void*)g,
      (__attribute__((address_space(3))) void*)l, 16, 0, 0);
}

// ---------------- fp32 -> bf16 convert ----------------
__global__ __launch_bounds__(256) void cvt_bf16_k(const float* __restrict__ s,
                                                  u16* __restrict__ d, int n4) {
  int i = blockIdx.x * 256 + threadIdx.x;
  if (i < n4) {
    float4 v = ((const float4*)s)[i];
    ushort4 o;
    o.x = f2b(v.x); o.y = f2b(v.y); o.z = f2b(v.z); o.w = f2b(v.w);
    ((ushort4*)d)[i] = o;
  }
}

// ---------------- patchify + pos embed -> h fp32 + h_bf ----------------
__global__ __launch_bounds__(256) void patchify_k(
    const float* __restrict__ x, const int* __restrict__ mask,
    const float* __restrict__ pw, const float* __restrict__ pb,
    const float* __restrict__ pos, float* __restrict__ h, u16* __restrict__ hb)
{
  int g1 = blockIdx.x, b = blockIdx.y, tid = threadIdx.x;
  __shared__ float sX[64 * 17];
  __shared__ float sW[2048];
  for (int i = tid; i < 64 * 16; i += 256) {
    int r = i >> 4, c = i & 15;
    int gi = (b * 64 + r) * 4096 + g1 * 16 + c;
    sX[r * 17 + c] = mask[gi] ? 0.f : x[gi];
  }
  for (int i = tid; i < 2048; i += 256) sW[i] = pw[i];
  __syncthreads();
  for (int m = tid; m < 2048; m += 256) {
    int e = m >> 5, g0 = m & 31;
    float acc = pb[e];
    const float* w = &sW[e * 32];
#pragma unroll
    for (int kh = 0; kh < 2; ++kh)
#pragma unroll
      for (int kw = 0; kw < 16; ++kw)
        acc += sX[(2 * g0 + kh) * 17 + kw] * w[kh * 16 + kw];
    float v = acc + pos[g1 * 2048 + m];
    long o = ((long)b * 256 + g1) * 2048 + m;
    h[o] = v;
    hb[o] = f2b(v);
  }
}

// ========== 256x256x(BK=64) 8-wave MFMA GEMM for in_proj ====================
// Coarse counted-vmcnt structure + fused conv1d/SiLU epilogue (xc half).
__global__ __launch_bounds__(512, 2) void gemm256_k(
    const u16* __restrict__ A0,               // h_bf (2048 x 2048)
    const u16* __restrict__ B0, long bStride, // Wip_bf (8192 x 2048) per dir
    u16* __restrict__ C0, long cStride,       // xz_bf (2048 x 8192) per dir
    const float* __restrict__ cw,             // conv weights (2,4096,4)
    const float* __restrict__ cb,             // conv bias (2,4096)
    u16* __restrict__ ub)                     // u_bf (2,8,256,4096)
{
  constexpr int K = 2048, N = 8192, LDA = 2048;
  __shared__ __align__(16) u16 lds[67584];
  u16* As = lds;
  u16* Bs = lds + 32768;
  const int dir = blockIdx.z;
  const u16* A = A0;
  const u16* B = B0 + (long)dir * bStride;
  u16* C = C0 + (long)dir * cStride;
  const int flip = dir;

  const int tid = threadIdx.x;
  const int wave = tid >> 6, lane = tid & 63;
  const int wr = wave >> 2, wc = wave & 3;
  const int bm = blockIdx.y * 256, bn = blockIdx.x * 256;
  const int lr = lane & 15, lq = lane >> 4;

  f32x4 acc[8][4];
#pragma unroll
  for (int i = 0; i < 8; ++i)
#pragma unroll
    for (int j = 0; j < 4; ++j) acc[i][j] = (f32x4){0.f, 0.f, 0.f, 0.f};

  auto stage = [&](int buf, int kt) {
    int k0 = kt << 6;
#pragma unroll
    for (int hf = 0; hf < 2; ++hf)
#pragma unroll
      for (int j = 0; j < 2; ++j) {
        int g = j * 512 + tid;
        int rl = hf * 128 + (g >> 3);
        int gr = (g & 7) ^ ((g >> 3) & 7);
        int ar = flip ? (bm + 255 - rl) : (bm + rl);
        gload_lds16(A + (long)ar * LDA + k0 + gr * 8,
                    &As[buf * 16384 + hf * 8192 + g * 8]);
        gload_lds16(B + (long)(bn + rl) * K + k0 + gr * 8,
                    &Bs[buf * 16384 + hf * 8192 + g * 8]);
      }
  };

  const int nk = K >> 6;
  stage(0, 0);
  for (int kt = 0; kt < nk; ++kt) {
    __builtin_amdgcn_s_barrier();
    __builtin_amdgcn_sched_barrier(0);
    if (kt + 1 < nk) {
      stage((kt + 1) & 1, kt + 1);
      asm volatile("s_waitcnt vmcnt(16)" ::: "memory");
    } else {
      asm volatile("s_waitcnt vmcnt(0)" ::: "memory");
    }
    __builtin_amdgcn_sched_barrier(0);
    __builtin_amdgcn_s_barrier();
    __builtin_amdgcn_sched_barrier(0);
    const int buf = kt & 1;
#pragma unroll
    for (int h = 0; h < 2; ++h) {
      bf16x8 av[8], bv[4];
#pragma unroll
      for (int i = 0; i < 8; ++i) {
        int row = wr * 128 + i * 16 + lr;
        av[i] = *(const bf16x8*)
            &As[buf * 16384 + ((row * 64 + h * 32 + lq * 8) ^ ((row & 7) << 3))];
      }
#pragma unroll
      for (int j = 0; j < 4; ++j) {
        int row = wc * 64 + j * 16 + lr;
        bv[j] = *(const bf16x8*)
            &Bs[buf * 16384 + ((row * 64 + h * 32 + lq * 8) ^ ((row & 7) << 3))];
      }
      __builtin_amdgcn_s_setprio(1);
#pragma unroll
      for (int i = 0; i < 8; ++i)
#pragma unroll
        for (int j = 0; j < 4; ++j)
          acc[i][j] = __builtin_amdgcn_mfma_f32_16x16x32_bf16(
              av[i], bv[j], acc[i][j], 0, 0, 0);
      __builtin_amdgcn_s_setprio(0);
    }
  }

  if (bn < 4096) {
    // ---- fused conv1d + SiLU epilogue (xc half) ----
    __syncthreads();
    u16* tile = lds;                 // [256][264] bf16
#pragma unroll
    for (int i = 0; i < 8; ++i) {
      int r0 = wr * 128 + i * 16 + lq * 4;
#pragma unroll
      for (int j = 0; j < 4; ++j) {
        int col = wc * 64 + j * 16 + lr;
        f32x4 v = acc[i][j];
#pragma unroll
        for (int r = 0; r < 4; ++r)
          tile[(r0 + r) * 264 + col] = f2b(v[r]);
      }
    }
    __syncthreads();
    const int rgrp = tid >> 5, c8 = tid & 31;
    const int d0 = bn + c8 * 8;
    float wv0[8], wv1[8], wv2[8], wv3[8], cbv[8];
#pragma unroll
    for (int e = 0; e < 8; ++e) {
      const float4 wq = *(const float4*)(cw + ((long)dir * 4096 + d0 + e) * 4);
      wv0[e] = wq.x; wv1[e] = wq.y; wv2[e] = wq.z; wv3[e] = wq.w;
      cbv[e] = cb[dir * 4096 + d0 + e];
    }
    const int l0 = rgrp * 16;
    float w0[8], w1[8], w2[8];
#pragma unroll
    for (int e = 0; e < 8; ++e) { w0[e] = 0.f; w1[e] = 0.f; w2[e] = 0.f; }
    if (rgrp > 0) {
      bf16x8 t0 = *(const bf16x8*)&tile[(l0 - 3) * 264 + c8 * 8];
      bf16x8 t1 = *(const bf16x8*)&tile[(l0 - 2) * 264 + c8 * 8];
      bf16x8 t2 = *(const bf16x8*)&tile[(l0 - 1) * 264 + c8 * 8];
#pragma unroll
      for (int e = 0; e < 8; ++e) {
        w0[e] = b2f((u16)t0[e]); w1[e] = b2f((u16)t1[e]); w2[e] = b2f((u16)t2[e]);
      }
    }
    long ubase = ((long)(dir * 8 + blockIdx.y) * 256 + l0) * 4096 + d0;
#pragma unroll
    for (int l = 0; l < 16; ++l) {
      bf16x8 t = *(const bf16x8*)&tile[(l0 + l) * 264 + c8 * 8];
      float cur[8];
#pragma unroll
      for (int e = 0; e < 8; ++e) cur[e] = b2f((u16)t[e]);
      bf16x8 ov;
#pragma unroll
      for (int e = 0; e < 8; ++e) {
        float a = cbv[e] + wv0[e] * w0[e] + wv1[e] * w1[e] + wv2[e] * w2[e] +
                  wv3[e] * cur[e];
        ov[e] = (short)f2b(a / (1.f + __expf(-a)));
      }
      *(bf16x8*)(ub + ubase + (long)l * 4096) = ov;
#pragma unroll
      for (int e = 0; e < 8; ++e) { w0[e] = w1[e]; w1[e] = w2[e]; w2[e] = cur[e]; }
    }
  } else {
#pragma unroll
    for (int i = 0; i < 8; ++i) {
      int r0 = bm + wr * 128 + i * 16 + lq * 4;
#pragma unroll
      for (int j = 0; j < 4; ++j) {
        int col = bn + wc * 64 + j * 16 + lr;
        f32x4 v = acc[i][j];
#pragma unroll
        for (int r = 0; r < 4; ++r)
          C[(long)(r0 + r) * N + col] = f2b(v[r]);
      }
    }
  }
}

// ---------------- bf16 MFMA GEMM (128x128, m97 structure) ----------------
template <int EPI, int F32OUT, int BFOUT>
__global__ __launch_bounds__(256) void mfma_gemm_k(
    const u16* __restrict__ A0, long aStride,
    const u16* __restrict__ B0, long bStride,
    float* __restrict__ C0, long cStride,
    u16* __restrict__ Cb0, long cbStride,
    const float* __restrict__ bias0, int biasStride,
    int N, int K, int lda, int flipDir1)
{
  __shared__ __align__(16) u16 As[2][4096];
  __shared__ __align__(16) u16 Bs[2][4096];
  const int dir = blockIdx.z;
  const u16* A = A0 + (long)dir * aStride;
  const u16* B = B0 + (long)dir * bStride;
  float* C = F32OUT ? (C0 + (long)dir * cStride) : nullptr;
  u16* Cb = BFOUT ? (Cb0 + (long)dir * cbStride) : nullptr;
  const float* bias = (EPI == 1) ? (bias0 + (long)dir * biasStride) : nullptr;
  const int flip = flipDir1 && (dir == 1);

  const int tid = threadIdx.x;
  const int wave = tid >> 6, lane = tid & 63;
  const int wr = wave >> 1, wc = wave & 1;
  const int bm = blockIdx.y * 128, bn = blockIdx.x * 128;
  const int lr = lane & 15, lq = lane >> 4;

  f32x4 acc[4][4];
#pragma unroll
  for (int i = 0; i < 4; ++i)
#pragma unroll
    for (int j = 0; j < 4; ++j) acc[i][j] = (f32x4){0.f, 0.f, 0.f, 0.f};

  const int nk = K >> 5;

  auto stage = [&](int buf, int k0) {
#pragma unroll
    for (int iss = 0; iss < 2; ++iss) {
      int ob = wave * 2048 + iss * 1024 + lane * 16;
      int row = ob >> 6, kb = (ob >> 4) & 3;
      int rg = bm + row;
      rg = flip ? ((rg & ~255) | (255 - (rg & 255))) : rg;
      gload_lds16(A + (long)rg * lda + k0 + kb * 8,
                  &As[buf][wave * 1024 + iss * 512]);
      int rb = bn + row; rb = (rb < N) ? rb : (N - 1);
      gload_lds16(B + (long)rb * K + k0 + kb * 8,
                  &Bs[buf][wave * 1024 + iss * 512]);
    }
  };

  stage(0, 0);
  for (int kt = 0; kt < nk; ++kt) {
    __syncthreads();
    if (kt + 1 < nk) stage((kt + 1) & 1, (kt + 1) << 5);
    const int buf = kt & 1;
    bf16x8 av[4], bv[4];
#pragma unroll
    for (int i = 0; i < 4; ++i)
      av[i] = *(const bf16x8*)&As[buf][(wr * 64 + i * 16 + lr) * 32 + lq * 8];
#pragma unroll
    for (int j = 0; j < 4; ++j)
      bv[j] = *(const bf16x8*)&Bs[buf][(wc * 64 + j * 16 + lr) * 32 + lq * 8];
#pragma unroll
    for (int i = 0; i < 4; ++i)
#pragma unroll
      for (int j = 0; j < 4; ++j)
        acc[i][j] = __builtin_amdgcn_mfma_f32_16x16x32_bf16(av[i], bv[j],
                                                            acc[i][j], 0, 0, 0);
  }

#pragma unroll
  for (int i = 0; i < 4; ++i) {
    int r0 = bm + wr * 64 + i * 16 + lq * 4;
#pragma unroll
    for (int j = 0; j < 4; ++j) {
      int col = bn + wc * 64 + j * 16 + lr;
      if (col < N) {
        f32x4 v = acc[i][j];
#pragma unroll
        for (int r = 0; r < 4; ++r) {
          float xv = v[r];
          if (EPI == 1) {
            xv += bias[col];
            xv = (xv > 20.f) ? xv : log1pf(expf(xv));
          }
          if (F32OUT) C[(long)(r0 + r) * N + col] = xv;
          if (BFOUT) Cb[(long)(r0 + r) * N + col] = f2b(xv);
        }
      }
    }
  }
}

// ---------------- x_dbl split-K partial GEMM: part = u @ Wx^T (K/4 slice) ----
__global__ __launch_bounds__(256) void xdbl_part_k(
    const u16* __restrict__ ubf, const u16* __restrict__ Wxbf,
    float* __restrict__ part)
{
  __shared__ __align__(16) u16 As[2][4096];
  __shared__ __align__(16) u16 Bs[2][4096];
  const int dir = blockIdx.z >> 2, split = blockIdx.z & 3;
  const u16* A = ubf + (long)dir * 2048 * 4096;
  const u16* B = Wxbf + (long)dir * 160 * 4096;
  float* C = part + (long)blockIdx.z * 327680;   // 2048*160
  const int tid = threadIdx.x;
  const int wave = tid >> 6, lane = tid & 63;
  const int wr = wave >> 1, wc = wave & 1;
  const int bm = blockIdx.y * 128, bn = blockIdx.x * 128;
  const int lr = lane & 15, lq = lane >> 4;

  f32x4 acc[4][4];
#pragma unroll
  for (int i = 0; i < 4; ++i)
#pragma unroll
    for (int j = 0; j < 4; ++j) acc[i][j] = (f32x4){0.f, 0.f, 0.f, 0.f};

  auto stage = [&](int buf, int k0) {
#pragma unroll
    for (int iss = 0; iss < 2; ++iss) {
      int ob = wave * 2048 + iss * 1024 + lane * 16;
      int row = ob >> 6, kb = (ob >> 4) & 3;
      gload_lds16(A + (long)(bm + row) * 4096 + k0 + kb * 8,
                  &As[buf][wave * 1024 + iss * 512]);
      int rb = bn + row; rb = (rb < 160) ? rb : 159;
      gload_lds16(B + (long)rb * 4096 + k0 + kb * 8,
                  &Bs[buf][wave * 1024 + iss * 512]);
    }
  };

  const int kbase = split << 10;   // *1024
  stage(0, kbase);
  for (int kt = 0; kt < 32; ++kt) {
    __syncthreads();
    if (kt + 1 < 32) stage((kt + 1) & 1, kbase + ((kt + 1) << 5));
    const int buf = kt & 1;
    bf16x8 av[4], bv[4];
#pragma unroll
    for (int i = 0; i < 4; ++i)
      av[i] = *(const bf16x8*)&As[buf][(wr * 64 + i * 16 + lr) * 32 + lq * 8];
#pragma unroll
    for (int j = 0; j < 4; ++j)
      bv[j] = *(const bf16x8*)&Bs[buf][(wc * 64 + j * 16 + lr) * 32 + lq * 8];
#pragma unroll
    for (int i = 0; i < 4; ++i)
#pragma unroll
      for (int j = 0; j < 4; ++j)
        acc[i][j] = __builtin_amdgcn_mfma_f32_16x16x32_bf16(av[i], bv[j],
                                                            acc[i][j], 0, 0, 0);
  }

#pragma unroll
  for (int i = 0; i < 4; ++i) {
    int r0 = bm + wr * 64 + i * 16 + lq * 4;
#pragma unroll
    for (int j = 0; j < 4; ++j) {
      int col = bn + wc * 64 + j * 16 + lr;
      if (col < 160) {
        f32x4 v = acc[i][j];
#pragma unroll
        for (int r = 0; r < 4; ++r)
          C[(long)(r0 + r) * 160 + col] = v[r];
      }
    }
  }
}

// ---------------- x_dbl split-K reduce -> fp32 + bf16 ----------------
__global__ __launch_bounds__(256) void xdbl_reduce_k(
    const float* __restrict__ part, float* __restrict__ xdbl,
    u16* __restrict__ xdbl_bf)
{
  int i = blockIdx.x * 256 + threadIdx.x;  // over 2*327680
  if (i >= 655360) return;
  int dir = i / 327680, rem = i - dir * 327680;
  long pb = (long)dir * 4 * 327680 + rem;
  float s = part[pb] + part[pb + 327680] + part[pb + 2 * 327680] +
            part[pb + 3 * 327680];
  xdbl[i] = s;
  xdbl_bf[i] = f2b(s);
}

// ====== fused dt-GEMM (softplus) + local chunk scan (pass A) ================
// Block: 128 rows (4 chunks of one batch) x 128 d. GEMM K=128 (lda=160),
// then dt tile -> LDS (bf16), then per-(chunk,d) local scan from zero state.
// Writes: y_pre (bf16), cumulative dt (bf16, replaces raw dt), chunk
// end-states (fp32). grid (32, 16, 2), 256 threads.
__global__ __launch_bounds__(256) void dtscan_k(
    const u16* __restrict__ xdblbf, const u16* __restrict__ Wdtbf,
    const float* __restrict__ bdt, const u16* __restrict__ ubuf,
    const float* __restrict__ xdbl, const float* __restrict__ A_log,
    const float* __restrict__ Dpv, u16* __restrict__ ypre,
    u16* __restrict__ cumdt, float* __restrict__ stend)
{
  // union: GEMM uses [0..16383] u16 (As/Bs dbuf); scan uses tile[128][132]
  // (16896 u16) + sB/sC fp32 [128][16] each (8192 u16 apiece).
  __shared__ __align__(16) u16 lds[25088];
  u16* As = lds;            // [2][4096]
  u16* Bs = lds + 8192;     // [2][4096]
  const int dir = blockIdx.z;
  const u16* A = xdblbf + (long)dir * 2048 * 160;
  const u16* B = Wdtbf + (long)dir * 4096 * 128;
  const float* bias = bdt + dir * 4096;
  const int tid = threadIdx.x;
  const int wave = tid >> 6, lane = tid & 63;
  const int wr = wave >> 1, wc = wave & 1;
  const int bm = blockIdx.y * 128, bn = blockIdx.x * 128;
  const int lr = lane & 15, lq = lane >> 4;

  f32x4 acc[4][4];
#pragma unroll
  for (int i = 0; i < 4; ++i)
#pragma unroll
    for (int j = 0; j < 4; ++j) acc[i][j] = (f32x4){0.f, 0.f, 0.f, 0.f};

  auto stage = [&](int buf, int k0) {
#pragma unroll
    for (int iss = 0; iss < 2; ++iss) {
      int ob = wave * 2048 + iss * 1024 + lane * 16;
      int row = ob >> 6, kb = (ob >> 4) & 3;
      gload_lds16(A + (long)(bm + row) * 160 + k0 + kb * 8,
                  &As[buf * 4096 + wave * 1024 + iss * 512]);
      gload_lds16(B + (long)(bn + row) * 128 + k0 + kb * 8,
                  &Bs[buf * 4096 + wave * 1024 + iss * 512]);
    }
  };

  stage(0, 0);
  for (int kt = 0; kt < 4; ++kt) {
    __syncthreads();
    if (kt + 1 < 4) stage((kt + 1) & 1, (kt + 1) << 5);
    const int buf = kt & 1;
    bf16x8 av[4], bv[4];
#pragma unroll
    for (int i = 0; i < 4; ++i)
      av[i] = *(const bf16x8*)&As[buf * 4096 + (wr * 64 + i * 16 + lr) * 32 + lq * 8];
#pragma unroll
    for (int j = 0; j < 4; ++j)
      bv[j] = *(const bf16x8*)&Bs[buf * 4096 + (wc * 64 + j * 16 + lr) * 32 + lq * 8];
#pragma unroll
    for (int i = 0; i < 4; ++i)
#pragma unroll
      for (int j = 0; j < 4; ++j)
        acc[i][j] = __builtin_amdgcn_mfma_f32_16x16x32_bf16(av[i], bv[j],
                                                            acc[i][j], 0, 0, 0);
  }

  // ---- dt tile (softplus) -> LDS ----
  __syncthreads();
  u16* tile = lds;                          // [128][132] bf16
  float* sB = (float*)(lds + 16896);        // [128][16]
  float* sC = sB + 2048;                    // [128][16]
#pragma unroll
  for (int i = 0; i < 4; ++i) {
    int r0 = wr * 64 + i * 16 + lq * 4;
#pragma unroll
    for (int j = 0; j < 4; ++j) {
      int col = wc * 64 + j * 16 + lr;
      f32x4 v = acc[i][j];
#pragma unroll
      for (int r = 0; r < 4; ++r) {
        float xv = v[r] + bias[bn + col];
        xv = (xv > 20.f) ? xv : log1pf(expf(xv));
        tile[(r0 + r) * 132 + col] = f2b(xv);
      }
    }
  }

  const int db = dir * 8 + (bm >> 8);       // batch index
  const int l0 = bm & 255;                  // 0 or 128
  const int c0 = l0 >> 5;                   // 0 or 4
  long r160 = (long)db * 256 * 160;
  for (int i2 = tid; i2 < 2048; i2 += 256) {
    int row = i2 >> 4, s = i2 & 15;
    float2 bc = *(const float2*)&xdbl[r160 + (long)(l0 + row) * 160 + 128 + s * 2];
    // interleaved load trick not valid across B/C boundary; do plain loads:
    (void)bc;
    sB[row * 16 + s] = xdbl[r160 + (long)(l0 + row) * 160 + 128 + s];
    sC[row * 16 + s] = xdbl[r160 + (long)(l0 + row) * 160 + 144 + s];
  }
  __syncthreads();

  // ---- local scan: 2 lines per thread ----
  const int d_loc = tid & 127, half = tid >> 7;
  const int d_glob = bn + d_loc;
  float Aa[16];
  const float4* ap = (const float4*)(A_log + ((long)dir * 4096 + d_glob) * 16);
#pragma unroll
  for (int q = 0; q < 4; ++q) {
    float4 t = ap[q];
    Aa[q * 4 + 0] = -__expf(t.x); Aa[q * 4 + 1] = -__expf(t.y);
    Aa[q * 4 + 2] = -__expf(t.z); Aa[q * 4 + 3] = -__expf(t.w);
  }
  float Dpd = Dpv[dir * 4096 + d_glob];

#pragma unroll
  for (int pass = 0; pass < 2; ++pass) {
    const int c = c0 + half + pass * 2;
    const int lrow0 = (half + pass * 2) * 32;
    long base = (long)db * 256 * 4096 + (long)c * 32 * 4096 + d_glob;
    float st[16];
#pragma unroll
    for (int s = 0; s < 16; ++s) st[s] = 0.f;
    float cum = 0.f;
    for (int i = 0; i < 32; ++i) {
      float dtv = b2f(tile[(lrow0 + i) * 132 + d_loc]);
      float uv = b2f(ubuf[base + (long)i * 4096]);
      cum += dtv;
      cumdt[base + (long)i * 4096] = f2b(cum);
      float du = dtv * uv;
      float y = 0.f;
#pragma unroll
      for (int s = 0; s < 16; ++s) {
        st[s] = st[s] * __expf(dtv * Aa[s]) + du * sB[(lrow0 + i) * 16 + s];
        y += st[s] * sC[(lrow0 + i) * 16 + s];
      }
      ypre[base + (long)i * 4096] = f2b(y + uv * Dpd);
    }
    long eb = ((long)(db * 8 + c) * 4096 + d_glob) * 16;
    float4* ep = (float4*)(stend + eb);
#pragma unroll
    for (int q = 0; q < 4; ++q)
      ep[q] = make_float4(st[q * 4], st[q * 4 + 1], st[q * 4 + 2], st[q * 4 + 3]);
  }
}

// ---------------- scan pass B: chunk combine + correction + gating -----------
__global__ __launch_bounds__(512) void scan_b_k(
    const u16* __restrict__ cumdt, const u16* __restrict__ xzbf,
    const float* __restrict__ xdbl, const float* __restrict__ A_log,
    const float* __restrict__ stend, u16* __restrict__ ybuf)
{
  int blk = blockIdx.x;
  int dtile = blk & 63, b = (blk >> 6) & 7, dir = blk >> 9;
  int tid = threadIdx.x;
  int c = tid >> 6, dd = tid & 63;
  int d0 = dtile * 64, d = d0 + dd;
  int db = dir * 8 + b;

  __shared__ float sEnd[8][64][17];
  __shared__ float sT[8][64];
  __shared__ float sC[256][16];

  long eBase = (long)db * 8 * 65536;
  for (int i = tid; i < 8192; i += 512) {
    int cc = i >> 10, rem = i & 1023, dd2 = rem >> 4, s = rem & 15;
    sEnd[cc][dd2][s] = stend[eBase + (long)cc * 65536 + (long)(d0 + dd2) * 16 + s];
  }
  {
    int cc = tid >> 6, dd2 = tid & 63;
    sT[cc][dd2] = b2f(cumdt[((long)db * 256 + cc * 32 + 31) * 4096 + d0 + dd2]);
  }
  long r160 = (long)db * 256 * 160;
  for (int i = tid; i < 4096; i += 512) {
    int l = i >> 4, s = i & 15;
    sC[l][s] = xdbl[r160 + (long)l * 160 + 144 + s];
  }
  __syncthreads();

  float A[16];
  const float4* ap = (const float4*)(A_log + ((long)dir * 4096 + d) * 16);
#pragma unroll
  for (int q = 0; q < 4; ++q) {
    float4 t = ap[q];
    A[q * 4 + 0] = -__expf(t.x); A[q * 4 + 1] = -__expf(t.y);
    A[q * 4 + 2] = -__expf(t.z); A[q * 4 + 3] = -__expf(t.w);
  }
  float g[16];
#pragma unroll
  for (int s = 0; s < 16; ++s) g[s] = 0.f;
  for (int j = 0; j < c; ++j) {
    float Tj = sT[j][dd];
#pragma unroll
    for (int s = 0; s < 16; ++s)
      g[s] = g[s] * __expf(A[s] * Tj) + sEnd[j][dd][s];
  }

  long base  = (long)db * 256 * 4096 + (long)c * 32 * 4096 + d;
  long zbase = (long)db * 256 * 8192 + (long)c * 32 * 8192 + 4096 + d;
  if (c == 0) {
    for (int i = 0; i < 32; ++i) {
      float yp = b2f(ybuf[base + (long)i * 4096]);
      float zv = b2f(xzbf[zbase + (long)i * 8192]);
      float y = yp * (zv / (1.f + __expf(-zv)));
      ybuf[base + (long)i * 4096] = f2b(y);
    }
  } else {
    for (int i = 0; i < 32; ++i) {
      float cum = b2f(cumdt[base + (long)i * 4096]);
      float yp = b2f(ybuf[base + (long)i * 4096]);
      float corr = 0.f;
      const int l = c * 32 + i;
#pragma unroll
      for (int s = 0; s < 16; ++s)
        corr += sC[l][s] * __expf(A[s] * cum) * g[s];
      float zv = b2f(xzbf[zbase + (long)i * 8192]);
      float y = (yp + corr) * (zv / (1.f + __expf(-zv)));
      ybuf[base + (long)i * 4096] = f2b(y);
    }
  }
}

// ---------------- residual add (fwd + flipped rev) + LayerNorm ----------------
__global__ __launch_bounds__(256) void add_ln_k(
    const float* __restrict__ h, const float* __restrict__ o0,
    const float* __restrict__ o1, const float* __restrict__ g,
    const float* __restrict__ bta, float* __restrict__ h2)
{
  int row = blockIdx.x;
  int b = row >> 8, l = row & 255;
  long base = (long)row * 2048;
  long base1 = ((long)b * 256 + (255 - l)) * 2048;
  int t8 = threadIdx.x * 8;
  float v[8];
  float4 x0 = *(const float4*)(h + base + t8);
  float4 x1 = *(const float4*)(h + base + t8 + 4);
  float4 a0 = *(const float4*)(o0 + base + t8);
  float4 a1 = *(const float4*)(o0 + base + t8 + 4);
  float4 c0 = *(const float4*)(o1 + base1 + t8);
  float4 c1 = *(const float4*)(o1 + base1 + t8 + 4);
  v[0] = x0.x + a0.x + c0.x; v[1] = x0.y + a0.y + c0.y;
  v[2] = x0.z + a0.z + c0.z; v[3] = x0.w + a0.w + c0.w;
  v[4] = x1.x + a1.x + c1.x; v[5] = x1.y + a1.y + c1.y;
  v[6] = x1.z + a1.z + c1.z; v[7] = x1.w + a1.w + c1.w;
  float s = 0.f, ss = 0.f;
#pragma unroll
  for (int j = 0; j < 8; ++j) { s += v[j]; ss += v[j] * v[j]; }
#pragma unroll
  for (int off = 32; off >= 1; off >>= 1) {
    s += __shfl_xor(s, off, 64);
    ss += __shfl_xor(ss, off, 64);
  }
  __shared__ float red[8];
  int wid = threadIdx.x >> 6, lane = threadIdx.x & 63;
  if (lane == 0) { red[wid] = s; red[wid + 4] = ss; }
  __syncthreads();
  if (threadIdx.x == 0) {
    red[0] = red[0] + red[1] + red[2] + red[3];
    red[4] = red[4] + red[5] + red[6] + red[7];
  }
  __syncthreads();
  float mean = red[0] * (1.f / 2048.f);
  float var = red[4] * (1.f / 2048.f) - mean * mean;
  float inv = rsqrtf(var + 1e-5f);
  float o[8];
#pragma unroll
  for (int j = 0; j < 8; ++j)
    o[j] = (v[j] - mean) * inv * g[t8 + j] + bta[t8 + j];
  *(float4*)(h2 + base + t8) = make_float4(o[0], o[1], o[2], o[3]);
  *(float4*)(h2 + base + t8 + 4) = make_float4(o[4], o[5], o[6], o[7]);
}

// ---------------- 31x31 "same" conv, 32x128 tile, bf16 LDS, 2x8/thread -------
__global__ __launch_bounds__(256) void dec_conv31_k(
    const float* __restrict__ h2, const float* __restrict__ kw,
    float* __restrict__ dc)
{
  __shared__ u16 sIn[62 * 168];
  __shared__ float sKw[961];
  int b = blockIdx.z;
  int l0 = blockIdx.y * 32;
  int m0 = blockIdx.x * 128;
  int tid = threadIdx.x;
  const float* src = h2 + (long)b * 256 * 2048;
  for (int i = tid; i < 961; i += 256) sKw[i] = kw[i];
  for (int i = tid; i < 62 * 168; i += 256) {
    int r = i / 168, c = i - r * 168;
    int gl = l0 + r - 15, gm = m0 + c - 15;
    float v = 0.f;
    if (c < 158 && gl >= 0 && gl < 256 && gm >= 0 && gm < 2048)
      v = src[(long)gl * 2048 + gm];
    sIn[i] = f2b(v);
  }
  __syncthreads();
  int tx = tid & 15, ty = tid >> 4;
  float acc[2][8];
#pragma unroll
  for (int r = 0; r < 2; ++r)
#pragma unroll
    for (int c = 0; c < 8; ++c) acc[r][c] = 0.f;

#pragma unroll 1
  for (int k = 0; k < 32; ++k) {
    const u16* rowp = &sIn[(ty * 2 + k) * 168 + tx * 8];
    float w[40];
#pragma unroll
    for (int q = 0; q < 5; ++q) {
      bf16x8 t = *(const bf16x8*)(rowp + q * 8);
#pragma unroll
      for (int e = 0; e < 8; ++e) w[q * 8 + e] = b2f((u16)t[e]);
    }
#pragma unroll
    for (int r = 0; r < 2; ++r) {
      unsigned ki = (unsigned)(k - r);
      if (ki > 30u) continue;
      const float* kwr = &sKw[ki * 31];
#pragma unroll
      for (int kj = 0; kj < 31; ++kj) {
        float kv = kwr[kj];
#pragma unroll
        for (int c = 0; c < 8; ++c) acc[r][c] += w[kj + c] * kv;
      }
    }
  }
#pragma unroll
  for (int r = 0; r < 2; ++r) {
    long obase = ((long)b * 256 + l0 + ty * 2 + r) * 2048 + m0 + tx * 8;
    *(float4*)(dc + obase) = make_float4(acc[r][0], acc[r][1], acc[r][2], acc[r][3]);
    *(float4*)(dc + obase + 4) = make_float4(acc[r][4], acc[r][5], acc[r][6], acc[r][7]);
  }
}

// ---------------- fused transposed conv (stride 2x16) ----------------
__global__ __launch_bounds__(256) void convT_k(
    const float* __restrict__ dc, const float* __restrict__ w,
    const float* __restrict__ wb, float* __restrict__ out)
{
  int j = blockIdx.x, b = blockIdx.y;
  __shared__ float sD[2048];
  __shared__ float sW[2048];
  int tid = threadIdx.x;
  const float* drow = dc + ((long)b * 256 + j) * 2048;
  for (int i = tid; i < 2048; i += 256) { sD[i] = drow[i]; sW[i] = w[i]; }
  __syncthreads();
  float cb = wb[0];
  int owlo = tid & 15, ohbase = tid >> 4;
#pragma unroll
  for (int q = 0; q < 4; ++q) {
    int oh = ohbase + q * 16;
    int i = oh >> 1, a = oh & 1;
    float acc = cb;
#pragma unroll 8
    for (int e = 0; e < 64; ++e)
      acc += sD[e * 32 + i] * sW[e * 32 + a * 16 + owlo];
    out[((long)b * 64 + oh) * 4096 + j * 16 + owlo] = acc;
  }
}

// ---------------- launcher ----------------
extern "C" void kernel_launch(void* const* d_in, const int* in_sizes, int n_in,
                              void* d_out, int out_size, void* d_ws, size_t ws_size,
                              hipStream_t stream)
{
  const float* x      = (const float*)d_in[0];
  const int*   mask   = (const int*)d_in[1];
  const float* proj_w = (const float*)d_in[2];
  const float* proj_b = (const float*)d_in[3];
  const float* pos    = (const float*)d_in[4];
  const float* Wip    = (const float*)d_in[5];   // (1,2,8192,2048)
  const float* convw  = (const float*)d_in[6];
  const float* convb  = (const float*)d_in[7];
  const float* Wx     = (const float*)d_in[8];   // (1,2,160,4096)
  const float* Wdt    = (const float*)d_in[9];   // (1,2,4096,128)
  const float* bdt    = (const float*)d_in[10];
  const float* Alog   = (const float*)d_in[11];
  const float* Dpv    = (const float*)d_in[12];
  const float* Wout   = (const float*)d_in[13];  // (1,2,2048,4096)
  const float* lng    = (const float*)d_in[14];
  const float* lnb    = (const float*)d_in[15];
  const float* dkw    = (const float*)d_in[16];
  const float* ctw    = (const float*)d_in[17];
  const float* ctb    = (const float*)d_in[18];
  float* out = (float*)d_out;

  // workspace layout (bytes)
  char* p = (char*)d_ws;
  u16*   xz_bf   = (u16*)p;            // z-half used; later ob fp32 alias
  float* ob      = (float*)p;
  p += 67108864;
  u16*   u_bf    = (u16*)p;            // later dc alias
  float* dc      = (float*)p;
  p += 33554432;
  u16*   cumdt_bf= (u16*)p; p += 67108864;     // 16.7M u16 (uses 33.5MB)
  float* xdbl    = (float*)p; p += 2621440;
  u16*   xdbl_bf = (u16*)p;  p += 1310720;
  float* h       = (float*)p; p += 16777216;
  u16*   h_bf    = (u16*)p;  p += 8388608;
  float* h2      = (float*)p; p += 16777216;
  u16*   y_bf    = (u16*)p;  p += 33554432;
  u16*   Wpool   = (u16*)p;  p += 67108864;    // Wip_bf; later Wout_bf (1st half)
  u16*   Wx_bf   = (u16*)p;  p += 2621440;
  u16*   Wdt_bf  = (u16*)p;  p += 2097152;

  // scratch aliases (temporally disjoint uses of the Wpool 2nd half):
  float* part   = (float*)(Wpool + 16777216);  // x_dbl split-K partials
  float* st_end = (float*)(Wpool + 16777216);  // scan chunk end-states

  // weight converts (Wip now; Wout later into same pool)
  cvt_bf16_k<<<32768, 256, 0, stream>>>(Wip, Wpool, 8388608);
  cvt_bf16_k<<<1280, 256, 0, stream>>>(Wx, Wx_bf, 327680);
  cvt_bf16_k<<<1024, 256, 0, stream>>>(Wdt, Wdt_bf, 262144);

  // 1) patchify + pos embed
  patchify_k<<<dim3(256, 8), 256, 0, stream>>>(x, mask, proj_w, proj_b, pos, h, h_bf);

  // 2) in_proj + fused conv1d/SiLU epilogue
  gemm256_k<<<dim3(32, 8, 2), 512, 0, stream>>>(
      h_bf, Wpool, (long)8192 * 2048, xz_bf, (long)2048 * 8192,
      convw, convb, u_bf);

  // 3) x_dbl = u @ Wx^T via split-K(4) + reduce (fp32 + bf16 mirror)
  xdbl_part_k<<<dim3(2, 16, 8), 256, 0, stream>>>(u_bf, Wx_bf, part);
  xdbl_reduce_k<<<2560, 256, 0, stream>>>(part, xdbl, xdbl_bf);

  // 4) fused dt-GEMM + local chunk scan (writes y_pre, cumdt, chunk states)
  dtscan_k<<<dim3(32, 16, 2), 256, 0, stream>>>(
      xdbl_bf, Wdt_bf, bdt, u_bf, xdbl, Alog, Dpv, y_bf, cumdt_bf, st_end);

  // 5) chunk combine + correction + gating
  scan_b_k<<<1024, 512, 0, stream>>>(cumdt_bf, xz_bf, xdbl, Alog, st_end, y_bf);

  // convert Wout into the (now dead) first half of Wpool
  cvt_bf16_k<<<16384, 256, 0, stream>>>(Wout, Wpool, 4194304);

  // 6) out = y @ Wout^T  (2048x2048, K=4096)  [ob aliases xz_bf region]
  mfma_gemm_k<0, 1, 0><<<dim3(16, 16, 2), 256, 0, stream>>>(
      y_bf, (long)2048 * 4096, Wpool, (long)2048 * 4096, ob, (long)2048 * 2048,
      nullptr, 0L, nullptr, 0, 2048, 4096, 4096, 0);

  // 7) h2 = LN(h + o_fwd + flip(o_rev))
  add_ln_k<<<2048, 256, 0, stream>>>(h, ob, ob + (long)2048 * 2048, lng, lnb, h2);

  // 8) 31x31 same conv -> dc  [aliases u_bf region, dead]
  dec_conv31_k<<<dim3(16, 8, 8), 256, 0, stream>>>(h2, dkw, dc);

  // 9) fused transposed conv -> rec
  convT_k<<<dim3(256, 8), 256, 0, stream>>>(dc, ctw, ctb, out);

  // 10) second output: x passthrough
  hipMemcpyAsync(out + 2097152, x, (size_t)2097152 * 4,
                 hipMemcpyDeviceToDevice, stream);
}

// Round 14
// 636.637 us; speedup vs baseline: 1.0973x; 1.0973x over previous
//
#include <hip/hip_runtime.h>
#include <hip/hip_bf16.h>
#include <math.h>

typedef unsigned short u16;
typedef __attribute__((ext_vector_type(8))) short bf16x8;
typedef __attribute__((ext_vector_type(4))) float f32x4;

__device__ __forceinline__ float b2f(u16 v) {
  unsigned u = ((unsigned)v) << 16;
  return __builtin_bit_cast(float, u);
}
__device__ __forceinline__ u16 f2b(float f) {
  unsigned u = __builtin_bit_cast(unsigned, f);
  unsigned r = u + 0x7fffu + ((u >> 16) & 1u);
  return (u16)(r >> 16);
}
__device__ __forceinline__ void gload_lds16(const u16* g, u16* l) {
  __builtin_amdgcn_global_load_lds(
      (const __attribute__((address_space(1))) void*)g,
      (__attribute__((address_space(3))) void*)l, 16, 0, 0);
}

// ---------------- fp32 -> bf16 convert ----------------
__global__ __launch_bounds__(256) void cvt_bf16_k(const float* __restrict__ s,
                                                  u16* __restrict__ d, int n4) {
  int i = blockIdx.x * 256 + threadIdx.x;
  if (i < n4) {
    float4 v = ((const float4*)s)[i];
    ushort4 o;
    o.x = f2b(v.x); o.y = f2b(v.y); o.z = f2b(v.z); o.w = f2b(v.w);
    ((ushort4*)d)[i] = o;
  }
}

// ---------------- Toeplitz expansion of 31x31 kernel ----------------
// tb[ki*1024 + h*512 + n*32 + k] = w[ki, h*32+k-n] if 0<=.<=30 else 0
__global__ __launch_bounds__(256) void toeplitz_k(
    const float* __restrict__ kw, u16* __restrict__ tb)
{
  int i = blockIdx.x * 256 + threadIdx.x;
  if (i >= 31744) return;
  int k = i & 31, n = (i >> 5) & 15, h = (i >> 9) & 1, ki = i >> 10;
  int t = h * 32 + k - n;
  float v = (t >= 0 && t <= 30) ? kw[ki * 31 + t] : 0.f;
  tb[i] = f2b(v);
}

// ---------------- patchify + pos embed -> h fp32 + h_bf ----------------
__global__ __launch_bounds__(256) void patchify_k(
    const float* __restrict__ x, const int* __restrict__ mask,
    const float* __restrict__ pw, const float* __restrict__ pb,
    const float* __restrict__ pos, float* __restrict__ h, u16* __restrict__ hb)
{
  int g1 = blockIdx.x, b = blockIdx.y, tid = threadIdx.x;
  __shared__ float sX[64 * 17];
  __shared__ float sW[2048];
  for (int i = tid; i < 64 * 16; i += 256) {
    int r = i >> 4, c = i & 15;
    int gi = (b * 64 + r) * 4096 + g1 * 16 + c;
    sX[r * 17 + c] = mask[gi] ? 0.f : x[gi];
  }
  for (int i = tid; i < 2048; i += 256) sW[i] = pw[i];
  __syncthreads();
  for (int m = tid; m < 2048; m += 256) {
    int e = m >> 5, g0 = m & 31;
    float acc = pb[e];
    const float* w = &sW[e * 32];
#pragma unroll
    for (int kh = 0; kh < 2; ++kh)
#pragma unroll
      for (int kw = 0; kw < 16; ++kw)
        acc += sX[(2 * g0 + kh) * 17 + kw] * w[kh * 16 + kw];
    float v = acc + pos[g1 * 2048 + m];
    long o = ((long)b * 256 + g1) * 2048 + m;
    h[o] = v;
    hb[o] = f2b(v);
  }
}

// ========== 256x256x(BK=64) 8-wave MFMA GEMM for in_proj ====================
// Coarse counted-vmcnt structure + fused conv1d/SiLU epilogue (xc half).
__global__ __launch_bounds__(512, 2) void gemm256_k(
    const u16* __restrict__ A0,               // h_bf (2048 x 2048)
    const u16* __restrict__ B0, long bStride, // Wip_bf (8192 x 2048) per dir
    u16* __restrict__ C0, long cStride,       // xz_bf (2048 x 8192) per dir
    const float* __restrict__ cw,             // conv weights (2,4096,4)
    const float* __restrict__ cb,             // conv bias (2,4096)
    u16* __restrict__ ub)                     // u_bf (2,8,256,4096)
{
  constexpr int K = 2048, N = 8192, LDA = 2048;
  __shared__ __align__(16) u16 lds[67584];
  u16* As = lds;
  u16* Bs = lds + 32768;
  const int dir = blockIdx.z;
  const u16* A = A0;
  const u16* B = B0 + (long)dir * bStride;
  u16* C = C0 + (long)dir * cStride;
  const int flip = dir;

  const int tid = threadIdx.x;
  const int wave = tid >> 6, lane = tid & 63;
  const int wr = wave >> 2, wc = wave & 3;
  const int bm = blockIdx.y * 256, bn = blockIdx.x * 256;
  const int lr = lane & 15, lq = lane >> 4;

  f32x4 acc[8][4];
#pragma unroll
  for (int i = 0; i < 8; ++i)
#pragma unroll
    for (int j = 0; j < 4; ++j) acc[i][j] = (f32x4){0.f, 0.f, 0.f, 0.f};

  auto stage = [&](int buf, int kt) {
    int k0 = kt << 6;
#pragma unroll
    for (int hf = 0; hf < 2; ++hf)
#pragma unroll
      for (int j = 0; j < 2; ++j) {
        int g = j * 512 + tid;
        int rl = hf * 128 + (g >> 3);
        int gr = (g & 7) ^ ((g >> 3) & 7);
        int ar = flip ? (bm + 255 - rl) : (bm + rl);
        gload_lds16(A + (long)ar * LDA + k0 + gr * 8,
                    &As[buf * 16384 + hf * 8192 + g * 8]);
        gload_lds16(B + (long)(bn + rl) * K + k0 + gr * 8,
                    &Bs[buf * 16384 + hf * 8192 + g * 8]);
      }
  };

  const int nk = K >> 6;
  stage(0, 0);
  for (int kt = 0; kt < nk; ++kt) {
    __builtin_amdgcn_s_barrier();
    __builtin_amdgcn_sched_barrier(0);
    if (kt + 1 < nk) {
      stage((kt + 1) & 1, kt + 1);
      asm volatile("s_waitcnt vmcnt(16)" ::: "memory");
    } else {
      asm volatile("s_waitcnt vmcnt(0)" ::: "memory");
    }
    __builtin_amdgcn_sched_barrier(0);
    __builtin_amdgcn_s_barrier();
    __builtin_amdgcn_sched_barrier(0);
    const int buf = kt & 1;
#pragma unroll
    for (int h = 0; h < 2; ++h) {
      bf16x8 av[8], bv[4];
#pragma unroll
      for (int i = 0; i < 8; ++i) {
        int row = wr * 128 + i * 16 + lr;
        av[i] = *(const bf16x8*)
            &As[buf * 16384 + ((row * 64 + h * 32 + lq * 8) ^ ((row & 7) << 3))];
      }
#pragma unroll
      for (int j = 0; j < 4; ++j) {
        int row = wc * 64 + j * 16 + lr;
        bv[j] = *(const bf16x8*)
            &Bs[buf * 16384 + ((row * 64 + h * 32 + lq * 8) ^ ((row & 7) << 3))];
      }
      __builtin_amdgcn_s_setprio(1);
#pragma unroll
      for (int i = 0; i < 8; ++i)
#pragma unroll
        for (int j = 0; j < 4; ++j)
          acc[i][j] = __builtin_amdgcn_mfma_f32_16x16x32_bf16(
              av[i], bv[j], acc[i][j], 0, 0, 0);
      __builtin_amdgcn_s_setprio(0);
    }
  }

  if (bn < 4096) {
    __syncthreads();
    u16* tile = lds;                 // [256][264] bf16
#pragma unroll
    for (int i = 0; i < 8; ++i) {
      int r0 = wr * 128 + i * 16 + lq * 4;
#pragma unroll
      for (int j = 0; j < 4; ++j) {
        int col = wc * 64 + j * 16 + lr;
        f32x4 v = acc[i][j];
#pragma unroll
        for (int r = 0; r < 4; ++r)
          tile[(r0 + r) * 264 + col] = f2b(v[r]);
      }
    }
    __syncthreads();
    const int rgrp = tid >> 5, c8 = tid & 31;
    const int d0 = bn + c8 * 8;
    float wv0[8], wv1[8], wv2[8], wv3[8], cbv[8];
#pragma unroll
    for (int e = 0; e < 8; ++e) {
      const float4 wq = *(const float4*)(cw + ((long)dir * 4096 + d0 + e) * 4);
      wv0[e] = wq.x; wv1[e] = wq.y; wv2[e] = wq.z; wv3[e] = wq.w;
      cbv[e] = cb[dir * 4096 + d0 + e];
    }
    const int l0 = rgrp * 16;
    float w0[8], w1[8], w2[8];
#pragma unroll
    for (int e = 0; e < 8; ++e) { w0[e] = 0.f; w1[e] = 0.f; w2[e] = 0.f; }
    if (rgrp > 0) {
      bf16x8 t0 = *(const bf16x8*)&tile[(l0 - 3) * 264 + c8 * 8];
      bf16x8 t1 = *(const bf16x8*)&tile[(l0 - 2) * 264 + c8 * 8];
      bf16x8 t2 = *(const bf16x8*)&tile[(l0 - 1) * 264 + c8 * 8];
#pragma unroll
      for (int e = 0; e < 8; ++e) {
        w0[e] = b2f((u16)t0[e]); w1[e] = b2f((u16)t1[e]); w2[e] = b2f((u16)t2[e]);
      }
    }
    long ubase = ((long)(dir * 8 + blockIdx.y) * 256 + l0) * 4096 + d0;
#pragma unroll
    for (int l = 0; l < 16; ++l) {
      bf16x8 t = *(const bf16x8*)&tile[(l0 + l) * 264 + c8 * 8];
      float cur[8];
#pragma unroll
      for (int e = 0; e < 8; ++e) cur[e] = b2f((u16)t[e]);
      bf16x8 ov;
#pragma unroll
      for (int e = 0; e < 8; ++e) {
        float a = cbv[e] + wv0[e] * w0[e] + wv1[e] * w1[e] + wv2[e] * w2[e] +
                  wv3[e] * cur[e];
        ov[e] = (short)f2b(a / (1.f + __expf(-a)));
      }
      *(bf16x8*)(ub + ubase + (long)l * 4096) = ov;
#pragma unroll
      for (int e = 0; e < 8; ++e) { w0[e] = w1[e]; w1[e] = w2[e]; w2[e] = cur[e]; }
    }
  } else {
#pragma unroll
    for (int i = 0; i < 8; ++i) {
      int r0 = bm + wr * 128 + i * 16 + lq * 4;
#pragma unroll
      for (int j = 0; j < 4; ++j) {
        int col = bn + wc * 64 + j * 16 + lr;
        f32x4 v = acc[i][j];
#pragma unroll
        for (int r = 0; r < 4; ++r)
          C[(long)(r0 + r) * N + col] = f2b(v[r]);
      }
    }
  }
}

// ---------------- bf16 MFMA GEMM (128x128, m97 structure) ----------------
template <int EPI, int F32OUT, int BFOUT>
__global__ __launch_bounds__(256) void mfma_gemm_k(
    const u16* __restrict__ A0, long aStride,
    const u16* __restrict__ B0, long bStride,
    float* __restrict__ C0, long cStride,
    u16* __restrict__ Cb0, long cbStride,
    const float* __restrict__ bias0, int biasStride,
    int N, int K, int lda, int flipDir1)
{
  __shared__ __align__(16) u16 As[2][4096];
  __shared__ __align__(16) u16 Bs[2][4096];
  const int dir = blockIdx.z;
  const u16* A = A0 + (long)dir * aStride;
  const u16* B = B0 + (long)dir * bStride;
  float* C = F32OUT ? (C0 + (long)dir * cStride) : nullptr;
  u16* Cb = BFOUT ? (Cb0 + (long)dir * cbStride) : nullptr;
  const float* bias = (EPI == 1) ? (bias0 + (long)dir * biasStride) : nullptr;
  const int flip = flipDir1 && (dir == 1);

  const int tid = threadIdx.x;
  const int wave = tid >> 6, lane = tid & 63;
  const int wr = wave >> 1, wc = wave & 1;
  const int bm = blockIdx.y * 128, bn = blockIdx.x * 128;
  const int lr = lane & 15, lq = lane >> 4;

  f32x4 acc[4][4];
#pragma unroll
  for (int i = 0; i < 4; ++i)
#pragma unroll
    for (int j = 0; j < 4; ++j) acc[i][j] = (f32x4){0.f, 0.f, 0.f, 0.f};

  const int nk = K >> 5;

  auto stage = [&](int buf, int k0) {
#pragma unroll
    for (int iss = 0; iss < 2; ++iss) {
      int ob = wave * 2048 + iss * 1024 + lane * 16;
      int row = ob >> 6, kb = (ob >> 4) & 3;
      int rg = bm + row;
      rg = flip ? ((rg & ~255) | (255 - (rg & 255))) : rg;
      gload_lds16(A + (long)rg * lda + k0 + kb * 8,
                  &As[buf][wave * 1024 + iss * 512]);
      int rb = bn + row; rb = (rb < N) ? rb : (N - 1);
      gload_lds16(B + (long)rb * K + k0 + kb * 8,
                  &Bs[buf][wave * 1024 + iss * 512]);
    }
  };

  stage(0, 0);
  for (int kt = 0; kt < nk; ++kt) {
    __syncthreads();
    if (kt + 1 < nk) stage((kt + 1) & 1, (kt + 1) << 5);
    const int buf = kt & 1;
    bf16x8 av[4], bv[4];
#pragma unroll
    for (int i = 0; i < 4; ++i)
      av[i] = *(const bf16x8*)&As[buf][(wr * 64 + i * 16 + lr) * 32 + lq * 8];
#pragma unroll
    for (int j = 0; j < 4; ++j)
      bv[j] = *(const bf16x8*)&Bs[buf][(wc * 64 + j * 16 + lr) * 32 + lq * 8];
#pragma unroll
    for (int i = 0; i < 4; ++i)
#pragma unroll
      for (int j = 0; j < 4; ++j)
        acc[i][j] = __builtin_amdgcn_mfma_f32_16x16x32_bf16(av[i], bv[j],
                                                            acc[i][j], 0, 0, 0);
  }

#pragma unroll
  for (int i = 0; i < 4; ++i) {
    int r0 = bm + wr * 64 + i * 16 + lq * 4;
#pragma unroll
    for (int j = 0; j < 4; ++j) {
      int col = bn + wc * 64 + j * 16 + lr;
      if (col < N) {
        f32x4 v = acc[i][j];
#pragma unroll
        for (int r = 0; r < 4; ++r) {
          float xv = v[r];
          if (EPI == 1) {
            xv += bias[col];
            xv = (xv > 20.f) ? xv : log1pf(expf(xv));
          }
          if (F32OUT) C[(long)(r0 + r) * N + col] = xv;
          if (BFOUT) Cb[(long)(r0 + r) * N + col] = f2b(xv);
        }
      }
    }
  }
}

// ---------------- x_dbl split-K partial GEMM ----------------
__global__ __launch_bounds__(256) void xdbl_part_k(
    const u16* __restrict__ ubf, const u16* __restrict__ Wxbf,
    float* __restrict__ part)
{
  __shared__ __align__(16) u16 As[2][4096];
  __shared__ __align__(16) u16 Bs[2][4096];
  const int dir = blockIdx.z >> 2, split = blockIdx.z & 3;
  const u16* A = ubf + (long)dir * 2048 * 4096;
  const u16* B = Wxbf + (long)dir * 160 * 4096;
  float* C = part + (long)blockIdx.z * 327680;
  const int tid = threadIdx.x;
  const int wave = tid >> 6, lane = tid & 63;
  const int wr = wave >> 1, wc = wave & 1;
  const int bm = blockIdx.y * 128, bn = blockIdx.x * 128;
  const int lr = lane & 15, lq = lane >> 4;

  f32x4 acc[4][4];
#pragma unroll
  for (int i = 0; i < 4; ++i)
#pragma unroll
    for (int j = 0; j < 4; ++j) acc[i][j] = (f32x4){0.f, 0.f, 0.f, 0.f};

  auto stage = [&](int buf, int k0) {
#pragma unroll
    for (int iss = 0; iss < 2; ++iss) {
      int ob = wave * 2048 + iss * 1024 + lane * 16;
      int row = ob >> 6, kb = (ob >> 4) & 3;
      gload_lds16(A + (long)(bm + row) * 4096 + k0 + kb * 8,
                  &As[buf][wave * 1024 + iss * 512]);
      int rb = bn + row; rb = (rb < 160) ? rb : 159;
      gload_lds16(B + (long)rb * 4096 + k0 + kb * 8,
                  &Bs[buf][wave * 1024 + iss * 512]);
    }
  };

  const int kbase = split << 10;
  stage(0, kbase);
  for (int kt = 0; kt < 32; ++kt) {
    __syncthreads();
    if (kt + 1 < 32) stage((kt + 1) & 1, kbase + ((kt + 1) << 5));
    const int buf = kt & 1;
    bf16x8 av[4], bv[4];
#pragma unroll
    for (int i = 0; i < 4; ++i)
      av[i] = *(const bf16x8*)&As[buf][(wr * 64 + i * 16 + lr) * 32 + lq * 8];
#pragma unroll
    for (int j = 0; j < 4; ++j)
      bv[j] = *(const bf16x8*)&Bs[buf][(wc * 64 + j * 16 + lr) * 32 + lq * 8];
#pragma unroll
    for (int i = 0; i < 4; ++i)
#pragma unroll
      for (int j = 0; j < 4; ++j)
        acc[i][j] = __builtin_amdgcn_mfma_f32_16x16x32_bf16(av[i], bv[j],
                                                            acc[i][j], 0, 0, 0);
  }

#pragma unroll
  for (int i = 0; i < 4; ++i) {
    int r0 = bm + wr * 64 + i * 16 + lq * 4;
#pragma unroll
    for (int j = 0; j < 4; ++j) {
      int col = bn + wc * 64 + j * 16 + lr;
      if (col < 160) {
        f32x4 v = acc[i][j];
#pragma unroll
        for (int r = 0; r < 4; ++r)
          C[(long)(r0 + r) * 160 + col] = v[r];
      }
    }
  }
}

// ---------------- x_dbl split-K reduce -> fp32 + bf16 ----------------
__global__ __launch_bounds__(256) void xdbl_reduce_k(
    const float* __restrict__ part, float* __restrict__ xdbl,
    u16* __restrict__ xdbl_bf)
{
  int i = blockIdx.x * 256 + threadIdx.x;
  if (i >= 655360) return;
  int dir = i / 327680, rem = i - dir * 327680;
  long pb = (long)dir * 4 * 327680 + rem;
  float s = part[pb] + part[pb + 327680] + part[pb + 2 * 327680] +
            part[pb + 3 * 327680];
  xdbl[i] = s;
  xdbl_bf[i] = f2b(s);
}

// ---------------- scan pass A: per-chunk local scan (zero init) --------------
__global__ __launch_bounds__(256) void scan_a_k(
    const u16* __restrict__ dtbuf, const u16* __restrict__ ubuf,
    const float* __restrict__ xdbl, const float* __restrict__ A_log,
    const float* __restrict__ Dpv, u16* __restrict__ ypre,
    float* __restrict__ stend, float* __restrict__ dtsum)
{
  int blk = blockIdx.x;
  int dtile = blk & 15, c = (blk >> 4) & 7, b = (blk >> 7) & 7, dir = blk >> 10;
  int tid = threadIdx.x;
  int d = dtile * 256 + tid;
  int db = dir * 8 + b;

  __shared__ float sB[32][16], sC[32][16];
  long r160 = (long)db * 256 * 160;
  for (int i = tid; i < 1024; i += 256) {
    int l = i >> 5, s = i & 31;
    float v = xdbl[r160 + (long)(c * 32 + l) * 160 + 128 + s];
    if (s < 16) sB[l][s] = v; else sC[l][s - 16] = v;
  }
  __syncthreads();

  float A[16], st[16];
  const float4* ap = (const float4*)(A_log + ((long)dir * 4096 + d) * 16);
#pragma unroll
  for (int q = 0; q < 4; ++q) {
    float4 t = ap[q];
    A[q * 4 + 0] = -__expf(t.x); A[q * 4 + 1] = -__expf(t.y);
    A[q * 4 + 2] = -__expf(t.z); A[q * 4 + 3] = -__expf(t.w);
  }
#pragma unroll
  for (int s = 0; s < 16; ++s) st[s] = 0.f;
  float Dpd = Dpv[dir * 4096 + d];

  long base = (long)db * 256 * 4096 + (long)c * 32 * 4096 + d;
  float dts = 0.f;
  for (int i = 0; i < 32; ++i) {
    float dtv = b2f(dtbuf[base + (long)i * 4096]);
    float uv  = b2f(ubuf[base + (long)i * 4096]);
    dts += dtv;
    float du = dtv * uv;
    float y = 0.f;
#pragma unroll
    for (int s = 0; s < 16; ++s) {
      st[s] = st[s] * __expf(dtv * A[s]) + du * sB[i][s];
      y += st[s] * sC[i][s];
    }
    ypre[base + (long)i * 4096] = f2b(y + uv * Dpd);
  }
  long eb = ((long)(db * 8 + c) * 4096 + d) * 16;
  float4* ep = (float4*)(stend + eb);
#pragma unroll
  for (int q = 0; q < 4; ++q)
    ep[q] = make_float4(st[q * 4], st[q * 4 + 1], st[q * 4 + 2], st[q * 4 + 3]);
  dtsum[(long)(db * 8 + c) * 4096 + d] = dts;
}

// ---------------- scan pass B: chunk combine + correction + gating -----------
__global__ __launch_bounds__(512) void scan_b_k(
    const u16* __restrict__ dtbuf, const u16* __restrict__ xzbf,
    const float* __restrict__ xdbl, const float* __restrict__ A_log,
    const float* __restrict__ stend, const float* __restrict__ dtsum,
    u16* __restrict__ ybuf)
{
  int blk = blockIdx.x;
  int dtile = blk & 63, b = (blk >> 6) & 7, dir = blk >> 9;
  int tid = threadIdx.x;
  int c = tid >> 6, dd = tid & 63;
  int d0 = dtile * 64, d = d0 + dd;
  int db = dir * 8 + b;

  __shared__ float sEnd[8][64][17];
  __shared__ float sT[8][64];
  __shared__ float sC[256][16];

  long eBase = (long)db * 8 * 65536;
  for (int i = tid; i < 8192; i += 512) {
    int cc = i >> 10, rem = i & 1023, dd2 = rem >> 4, s = rem & 15;
    sEnd[cc][dd2][s] = stend[eBase + (long)cc * 65536 + (long)(d0 + dd2) * 16 + s];
  }
  {
    int cc = tid >> 6, dd2 = tid & 63;
    sT[cc][dd2] = dtsum[(long)(db * 8 + cc) * 4096 + d0 + dd2];
  }
  long r160 = (long)db * 256 * 160;
  for (int i = tid; i < 4096; i += 512) {
    int l = i >> 4, s = i & 15;
    sC[l][s] = xdbl[r160 + (long)l * 160 + 144 + s];
  }
  __syncthreads();

  float A[16];
  const float4* ap = (const float4*)(A_log + ((long)dir * 4096 + d) * 16);
#pragma unroll
  for (int q = 0; q < 4; ++q) {
    float4 t = ap[q];
    A[q * 4 + 0] = -__expf(t.x); A[q * 4 + 1] = -__expf(t.y);
    A[q * 4 + 2] = -__expf(t.z); A[q * 4 + 3] = -__expf(t.w);
  }
  float g[16];
#pragma unroll
  for (int s = 0; s < 16; ++s) g[s] = 0.f;
  for (int j = 0; j < c; ++j) {
    float Tj = sT[j][dd];
#pragma unroll
    for (int s = 0; s < 16; ++s)
      g[s] = g[s] * __expf(A[s] * Tj) + sEnd[j][dd][s];
  }

  long base  = (long)db * 256 * 4096 + (long)c * 32 * 4096 + d;
  long zbase = (long)db * 256 * 8192 + (long)c * 32 * 8192 + 4096 + d;
  float cum = 0.f;
  if (c == 0) {
    for (int i = 0; i < 32; ++i) {
      float yp = b2f(ybuf[base + (long)i * 4096]);
      float zv = b2f(xzbf[zbase + (long)i * 8192]);
      float y = yp * (zv / (1.f + __expf(-zv)));
      ybuf[base + (long)i * 4096] = f2b(y);
    }
  } else {
    for (int i = 0; i < 32; ++i) {
      float dtv = b2f(dtbuf[base + (long)i * 4096]);
      cum += dtv;
      float yp = b2f(ybuf[base + (long)i * 4096]);
      float corr = 0.f;
      const int l = c * 32 + i;
#pragma unroll
      for (int s = 0; s < 16; ++s)
        corr += sC[l][s] * __expf(A[s] * cum) * g[s];
      float zv = b2f(xzbf[zbase + (long)i * 8192]);
      float y = (yp + corr) * (zv / (1.f + __expf(-zv)));
      ybuf[base + (long)i * 4096] = f2b(y);
    }
  }
}

// ---------------- residual add (fwd + flipped rev) + LayerNorm ----------------
__global__ __launch_bounds__(256) void add_ln_k(
    const float* __restrict__ h, const float* __restrict__ o0,
    const float* __restrict__ o1, const float* __restrict__ g,
    const float* __restrict__ bta, float* __restrict__ h2)
{
  int row = blockIdx.x;
  int b = row >> 8, l = row & 255;
  long base = (long)row * 2048;
  long base1 = ((long)b * 256 + (255 - l)) * 2048;
  int t8 = threadIdx.x * 8;
  float v[8];
  float4 x0 = *(const float4*)(h + base + t8);
  float4 x1 = *(const float4*)(h + base + t8 + 4);
  float4 a0 = *(const float4*)(o0 + base + t8);
  float4 a1 = *(const float4*)(o0 + base + t8 + 4);
  float4 c0 = *(const float4*)(o1 + base1 + t8);
  float4 c1 = *(const float4*)(o1 + base1 + t8 + 4);
  v[0] = x0.x + a0.x + c0.x; v[1] = x0.y + a0.y + c0.y;
  v[2] = x0.z + a0.z + c0.z; v[3] = x0.w + a0.w + c0.w;
  v[4] = x1.x + a1.x + c1.x; v[5] = x1.y + a1.y + c1.y;
  v[6] = x1.z + a1.z + c1.z; v[7] = x1.w + a1.w + c1.w;
  float s = 0.f, ss = 0.f;
#pragma unroll
  for (int j = 0; j < 8; ++j) { s += v[j]; ss += v[j] * v[j]; }
#pragma unroll
  for (int off = 32; off >= 1; off >>= 1) {
    s += __shfl_xor(s, off, 64);
    ss += __shfl_xor(ss, off, 64);
  }
  __shared__ float red[8];
  int wid = threadIdx.x >> 6, lane = threadIdx.x & 63;
  if (lane == 0) { red[wid] = s; red[wid + 4] = ss; }
  __syncthreads();
  if (threadIdx.x == 0) {
    red[0] = red[0] + red[1] + red[2] + red[3];
    red[4] = red[4] + red[5] + red[6] + red[7];
  }
  __syncthreads();
  float mean = red[0] * (1.f / 2048.f);
  float var = red[4] * (1.f / 2048.f) - mean * mean;
  float inv = rsqrtf(var + 1e-5f);
  float o[8];
#pragma unroll
  for (int j = 0; j < 8; ++j)
    o[j] = (v[j] - mean) * inv * g[t8 + j] + bta[t8 + j];
  *(float4*)(h2 + base + t8) = make_float4(o[0], o[1], o[2], o[3]);
  *(float4*)(h2 + base + t8 + 4) = make_float4(o[4], o[5], o[6], o[7]);
}

// ---------------- 31x31 "same" conv via MFMA Toeplitz ----------------
// Block: 64l x 64m outputs, 4 waves (one 16-l group each). Input halo tile
// 94x112 bf16 (stride 120). Per (ki,h): B-frag from global Toeplitz (L2),
// A-frag = one ds_read_b128 per m-subtile. 2 MFMA x 31 ki per 16x16 tile.
__global__ __launch_bounds__(256) void dec_conv31_k(
    const float* __restrict__ h2, const u16* __restrict__ tb,
    float* __restrict__ dc)
{
  __shared__ __align__(16) u16 sIn[94 * 120];   // 22560 B
  const int b = blockIdx.z;
  const int l0 = blockIdx.y * 64;
  const int m0 = blockIdx.x * 64;
  const int tid = threadIdx.x;
  const float* src = h2 + (long)b * 256 * 2048;
  for (int i = tid; i < 94 * 112; i += 256) {
    int r = i / 112, c = i - r * 112;
    int gl = l0 + r - 15, gm = m0 + c - 15;
    float v = 0.f;
    if (gl >= 0 && gl < 256 && gm >= 0 && gm < 2048)
      v = src[(long)gl * 2048 + gm];
    sIn[r * 120 + c] = f2b(v);
  }
  __syncthreads();
  const int wave = tid >> 6, lane = tid & 63;
  const int lr = lane & 15, lq = lane >> 4;

  f32x4 acc[4];
#pragma unroll
  for (int s = 0; s < 4; ++s) acc[s] = (f32x4){0.f, 0.f, 0.f, 0.f};

#pragma unroll 1
  for (int ki = 0; ki < 31; ++ki) {
    const u16* arow = &sIn[(wave * 16 + lr + ki) * 120];
#pragma unroll
    for (int h = 0; h < 2; ++h) {
      bf16x8 bv = *(const bf16x8*)&tb[((ki * 2 + h) * 16 + lr) * 32 + lq * 8];
#pragma unroll
      for (int ms = 0; ms < 4; ++ms) {
        bf16x8 av = *(const bf16x8*)&arow[ms * 16 + h * 32 + lq * 8];
        acc[ms] = __builtin_amdgcn_mfma_f32_16x16x32_bf16(av, bv, acc[ms], 0, 0, 0);
      }
    }
  }
#pragma unroll
  for (int ms = 0; ms < 4; ++ms) {
    f32x4 v = acc[ms];
#pragma unroll
    for (int r = 0; r < 4; ++r)
      dc[((long)b * 256 + l0 + wave * 16 + lq * 4 + r) * 2048 + m0 + ms * 16 + lr]
          = v[r];
  }
}

// ---------------- fused transposed conv (stride 2x16) ----------------
__global__ __launch_bounds__(256) void convT_k(
    const float* __restrict__ dc, const float* __restrict__ w,
    const float* __restrict__ wb, float* __restrict__ out)
{
  int j = blockIdx.x, b = blockIdx.y;
  __shared__ float sD[2048];
  __shared__ float sW[2048];
  int tid = threadIdx.x;
  const float* drow = dc + ((long)b * 256 + j) * 2048;
  for (int i = tid; i < 2048; i += 256) { sD[i] = drow[i]; sW[i] = w[i]; }
  __syncthreads();
  float cb = wb[0];
  int owlo = tid & 15, ohbase = tid >> 4;
#pragma unroll
  for (int q = 0; q < 4; ++q) {
    int oh = ohbase + q * 16;
    int i = oh >> 1, a = oh & 1;
    float acc = cb;
#pragma unroll 8
    for (int e = 0; e < 64; ++e)
      acc += sD[e * 32 + i] * sW[e * 32 + a * 16 + owlo];
    out[((long)b * 64 + oh) * 4096 + j * 16 + owlo] = acc;
  }
}

// ---------------- launcher ----------------
extern "C" void kernel_launch(void* const* d_in, const int* in_sizes, int n_in,
                              void* d_out, int out_size, void* d_ws, size_t ws_size,
                              hipStream_t stream)
{
  const float* x      = (const float*)d_in[0];
  const int*   mask   = (const int*)d_in[1];
  const float* proj_w = (const float*)d_in[2];
  const float* proj_b = (const float*)d_in[3];
  const float* pos    = (const float*)d_in[4];
  const float* Wip    = (const float*)d_in[5];   // (1,2,8192,2048)
  const float* convw  = (const float*)d_in[6];
  const float* convb  = (const float*)d_in[7];
  const float* Wx     = (const float*)d_in[8];   // (1,2,160,4096)
  const float* Wdt    = (const float*)d_in[9];   // (1,2,4096,128)
  const float* bdt    = (const float*)d_in[10];
  const float* Alog   = (const float*)d_in[11];
  const float* Dpv    = (const float*)d_in[12];
  const float* Wout   = (const float*)d_in[13];  // (1,2,2048,4096)
  const float* lng    = (const float*)d_in[14];
  const float* lnb    = (const float*)d_in[15];
  const float* dkw    = (const float*)d_in[16];  // (1,1,31,31)
  const float* ctw    = (const float*)d_in[17];
  const float* ctb    = (const float*)d_in[18];
  float* out = (float*)d_out;

  // workspace layout (bytes)
  char* p = (char*)d_ws;
  u16*   xz_bf   = (u16*)p;            // z-half used; later ob fp32 alias
  float* ob      = (float*)p;
  p += 67108864;
  u16*   u_bf    = (u16*)p;            // later dc alias
  float* dc      = (float*)p;
  p += 33554432;
  u16*   dt_bf   = (u16*)p; p += 67108864;
  float* xdbl    = (float*)p; p += 2621440;
  u16*   xdbl_bf = (u16*)p;  p += 1310720;
  float* h       = (float*)p; p += 16777216;
  u16*   h_bf    = (u16*)p;  p += 8388608;
  float* h2      = (float*)p; p += 16777216;   // also scan dtsum scratch
  u16*   y_bf    = (u16*)p;  p += 33554432;
  u16*   Wpool   = (u16*)p;  p += 67108864;    // Wip_bf; later Wout_bf (1st half)
  u16*   Wx_bf   = (u16*)p;  p += 2621440;
  u16*   Wdt_bf  = (u16*)p;  p += 2097152;
  u16*   tb      = (u16*)p;  p += 65536;       // Toeplitz tiles (63.5 KB)

  // scratch aliases (temporally disjoint uses of the Wpool 2nd half):
  float* part   = (float*)(Wpool + 16777216);  // x_dbl split-K partials
  float* st_end = (float*)(Wpool + 16777216);  // scan chunk end-states
  float* dtsum  = h2;                          // h2 not written until add_ln

  // weight converts + Toeplitz expansion
  cvt_bf16_k<<<32768, 256, 0, stream>>>(Wip, Wpool, 8388608);
  cvt_bf16_k<<<1280, 256, 0, stream>>>(Wx, Wx_bf, 327680);
  cvt_bf16_k<<<1024, 256, 0, stream>>>(Wdt, Wdt_bf, 262144);
  toeplitz_k<<<124, 256, 0, stream>>>(dkw, tb);

  // 1) patchify + pos embed
  patchify_k<<<dim3(256, 8), 256, 0, stream>>>(x, mask, proj_w, proj_b, pos, h, h_bf);

  // 2) in_proj + fused conv1d/SiLU epilogue
  gemm256_k<<<dim3(32, 8, 2), 512, 0, stream>>>(
      h_bf, Wpool, (long)8192 * 2048, xz_bf, (long)2048 * 8192,
      convw, convb, u_bf);

  // 3) x_dbl = u @ Wx^T via split-K(4) + reduce (fp32 + bf16 mirror)
  xdbl_part_k<<<dim3(2, 16, 8), 256, 0, stream>>>(u_bf, Wx_bf, part);
  xdbl_reduce_k<<<2560, 256, 0, stream>>>(part, xdbl, xdbl_bf);

  // 4) dt = softplus(x_dbl[:, :128] @ Wdt^T + bdt) -> bf16
  mfma_gemm_k<1, 0, 1><<<dim3(32, 16, 2), 256, 0, stream>>>(
      xdbl_bf, (long)2048 * 160, Wdt_bf, (long)4096 * 128, nullptr, 0L,
      dt_bf, (long)2048 * 4096, bdt, 4096, 4096, 128, 160, 0);

  // 5) chunked selective scan
  scan_a_k<<<2048, 256, 0, stream>>>(dt_bf, u_bf, xdbl, Alog, Dpv, y_bf, st_end, dtsum);
  scan_b_k<<<1024, 512, 0, stream>>>(dt_bf, xz_bf, xdbl, Alog, st_end, dtsum, y_bf);

  // convert Wout into the (now dead) first half of Wpool
  cvt_bf16_k<<<16384, 256, 0, stream>>>(Wout, Wpool, 4194304);

  // 6) out = y @ Wout^T  [ob aliases xz_bf region]
  mfma_gemm_k<0, 1, 0><<<dim3(16, 16, 2), 256, 0, stream>>>(
      y_bf, (long)2048 * 4096, Wpool, (long)2048 * 4096, ob, (long)2048 * 2048,
      nullptr, 0L, nullptr, 0, 2048, 4096, 4096, 0);

  // 7) h2 = LN(h + o_fwd + flip(o_rev))
  add_ln_k<<<2048, 256, 0, stream>>>(h, ob, ob + (long)2048 * 2048, lng, lnb, h2);

  // 8) 31x31 same conv via MFMA Toeplitz -> dc [aliases u_bf region, dead]
  dec_conv31_k<<<dim3(32, 4, 8), 256, 0, stream>>>(h2, tb, dc);

  // 9) fused transposed conv -> rec
  convT_k<<<dim3(256, 8), 256, 0, stream>>>(dc, ctw, ctb, out);

  // 10) second output: x passthrough
  hipMemcpyAsync(out + 2097152, x, (size_t)2097152 * 4,
                 hipMemcpyDeviceToDevice, stream);
}